// Round 3
// baseline (69.320 us; speedup 1.0000x reference)
//
#include <hip/hip_runtime.h>
#include <math.h>

#define LAT_CONST  ((float)(5.0 * 0.03 / 200.0 + 0.06))   // 0.06075
#define GRAD_CONST ((float)(1.0 / 0.06))                  // 16.666666...
#define SEND_CONST ((float)(2.0 / 3.0))                   // 0.666666...

// Kernel 1: tabulate g(t) = sigmoid(MLP([x3,x4,x5](t))).
// 4 partial accumulators break the 64-deep dependent FMA chain (only ~1 wave/SIMD
// is resident for this launch, so dep-latency is the limiter, not throughput).
__global__ void build_table_kernel(const float* __restrict__ W1, const float* __restrict__ b1,
                                   const float* __restrict__ W2, const float* __restrict__ b2,
                                   const float* __restrict__ W3, const float* __restrict__ b3,
                                   float* __restrict__ tbl, int n, float lo, float h)
{
    int i = blockIdx.x * blockDim.x + threadIdx.x;
    if (i >= n + 2) return;
    float t  = lo + (float)i * h;
    float x4 = t + LAT_CONST;
    float x5 = t * SEND_CONST;
    float x3 = x4 * GRAD_CONST;

    float h1[64];
#pragma unroll
    for (int j = 0; j < 64; ++j) {
        float acc = b1[j];
        acc = fmaf(x3, W1[j],       acc);
        acc = fmaf(x4, W1[64 + j],  acc);
        acc = fmaf(x5, W1[128 + j], acc);
        h1[j] = fmaxf(acc, 0.f);
    }

    float logit = b3[0];
    for (int j = 0; j < 64; ++j) {
        float a0 = 0.f, a1 = 0.f, a2 = 0.f, a3 = 0.f;
#pragma unroll
        for (int k = 0; k < 64; k += 4) {
            a0 = fmaf(h1[k + 0], W2[(k + 0) * 64 + j], a0);
            a1 = fmaf(h1[k + 1], W2[(k + 1) * 64 + j], a1);
            a2 = fmaf(h1[k + 2], W2[(k + 2) * 64 + j], a2);
            a3 = fmaf(h1[k + 3], W2[(k + 3) * 64 + j], a3);
        }
        float acc = b2[j] + ((a0 + a1) + (a2 + a3));
        logit = fmaf(fmaxf(acc, 0.f), W3[j], logit);
    }
    tbl[i] = 1.f / (1.f + expf(-logit));
}

// Kernel 2: coalesced LDS-staged row update.
// 1024 rows/block = 7168 floats = 1792 float4 = exactly 7 float4 per thread.
#define ROWS_PER_BLOCK 1024
#define BLOCK 256

__global__ __launch_bounds__(BLOCK)
void rows_kernel(const float* __restrict__ x, const float* __restrict__ tbl,
                 float* __restrict__ out, int B, int n, float lo, float inv_h)
{
    __shared__ float lds[ROWS_PER_BLOCK * 7];   // 28 KiB -> 5 blocks/CU
    const int tid = threadIdx.x;
    const long long rowBase = (long long)blockIdx.x * ROWS_PER_BLOCK;
    const int rows = min(ROWS_PER_BLOCK, (int)(B - rowBase));
    const int nfl  = rows * 7;
    const int nf4  = nfl >> 2;
    const size_t fBase = (size_t)rowBase * 7;   // multiple of 7168 -> 16B aligned

    // Coalesced float4 global -> LDS
    const float4* __restrict__ in4 = (const float4*)(x + fBase);
    float4* lds4 = (float4*)lds;
    for (int i = tid; i < nf4; i += BLOCK) lds4[i] = in4[i];
    for (int i = (nf4 << 2) + tid; i < nfl; i += BLOCK) lds[i] = x[fBase + i];
    __syncthreads();

    // Per-row recurrence from LDS. Lane stride = 7 dwords -> gcd(7,32)=1 ->
    // 2 lanes/bank for a wave64 access = conflict-free (m136).
    for (int r = tid; r < rows; r += BLOCK) {
        float* row = lds + r * 7;
        float x2 = row[2];
        float x6 = row[6];
        float f = (x6 <= 0.f) ? (x6 + 1.f) : (1.f - x6);   // loop constant
        float x3 = 0.f, x4 = 0.f, x5 = 0.f;
#pragma unroll
        for (int s = 0; s < 10; ++s) {
            float t = x2 * f;
            x4 = t + LAT_CONST;
            x5 = t * SEND_CONST;
            x3 = x4 * GRAD_CONST;
            float p = (t - lo) * inv_h;
            p = fminf(fmaxf(p, 0.f), (float)n);
            int   idx = (int)p;
            float fr  = p - (float)idx;
            float g0 = tbl[idx];
            float g1 = tbl[idx + 1];
            x2 = fmaf(g1 - g0, fr, g0);   // lerp = sigmoid(MLP(feat))
        }
        row[0] += 10.f;   // 10 steps of +1
        row[2] = x2;
        row[3] = x3;
        row[4] = x4;
        row[5] = x5;
        // row[1], row[6] pass through unchanged
    }
    __syncthreads();

    // Coalesced float4 LDS -> global
    float4* __restrict__ out4 = (float4*)(out + fBase);
    for (int i = tid; i < nf4; i += BLOCK) out4[i] = lds4[i];
    for (int i = (nf4 << 2) + tid; i < nfl; i += BLOCK) out[fBase + i] = lds[i];
}

extern "C" void kernel_launch(void* const* d_in, const int* in_sizes, int n_in,
                              void* d_out, int out_size, void* d_ws, size_t ws_size,
                              hipStream_t stream)
{
    const float* x  = (const float*)d_in[0];
    const float* W1 = (const float*)d_in[1];
    const float* b1 = (const float*)d_in[2];
    const float* W2 = (const float*)d_in[3];
    const float* b2 = (const float*)d_in[4];
    const float* W3 = (const float*)d_in[5];
    const float* b3 = (const float*)d_in[6];
    float* out = (float*)d_out;

    int B = in_sizes[0] / 7;

    // Table: 64K entries (256 KB, L2-resident). Degrade if ws is small.
    int n = 1 << 16;
    while ((size_t)(n + 2) * sizeof(float) > ws_size && n > 1024) n >>= 1;

    float* tbl = (float*)d_ws;
    const float lo = -24.f, hi = 24.f;
    float h     = (hi - lo) / (float)n;
    float inv_h = (float)n / (hi - lo);

    hipLaunchKernelGGL(build_table_kernel, dim3((n + 2 + 255) / 256), dim3(256), 0, stream,
                       W1, b1, W2, b2, W3, b3, tbl, n, lo, h);
    hipLaunchKernelGGL(rows_kernel, dim3((B + ROWS_PER_BLOCK - 1) / ROWS_PER_BLOCK), dim3(BLOCK),
                       0, stream, x, tbl, out, B, n, lo, inv_h);
}

// Round 4
// 67.953 us; speedup vs baseline: 1.0201x; 1.0201x over previous
//
#include <hip/hip_runtime.h>
#include <math.h>

#define LAT_CONST  ((float)(5.0 * 0.03 / 200.0 + 0.06))   // 0.06075
#define GRAD_CONST ((float)(1.0 / 0.06))                  // 16.666666...
#define SEND_CONST ((float)(2.0 / 3.0))                   // 0.666666...

// Kernel 1: tabulate g(t) = sigmoid(MLP([x3,x4,x5](t))) into a scalar table.
__global__ void build_table_kernel(const float* __restrict__ W1, const float* __restrict__ b1,
                                   const float* __restrict__ W2, const float* __restrict__ b2,
                                   const float* __restrict__ W3, const float* __restrict__ b3,
                                   float* __restrict__ tbl, int n, float lo, float h)
{
    int i = blockIdx.x * blockDim.x + threadIdx.x;
    if (i >= n + 2) return;
    float t  = lo + (float)i * h;
    float x4 = t + LAT_CONST;
    float x5 = t * SEND_CONST;
    float x3 = x4 * GRAD_CONST;

    float h1[64];
#pragma unroll
    for (int j = 0; j < 64; ++j) {
        float acc = b1[j];
        acc = fmaf(x3, W1[j],       acc);
        acc = fmaf(x4, W1[64 + j],  acc);
        acc = fmaf(x5, W1[128 + j], acc);
        h1[j] = fmaxf(acc, 0.f);
    }

    float logit = b3[0];
    for (int j = 0; j < 64; ++j) {
        float a0 = 0.f, a1 = 0.f, a2 = 0.f, a3 = 0.f;
#pragma unroll
        for (int k = 0; k < 64; k += 4) {
            a0 = fmaf(h1[k + 0], W2[(k + 0) * 64 + j], a0);
            a1 = fmaf(h1[k + 1], W2[(k + 1) * 64 + j], a1);
            a2 = fmaf(h1[k + 2], W2[(k + 2) * 64 + j], a2);
            a3 = fmaf(h1[k + 3], W2[(k + 3) * 64 + j], a3);
        }
        float acc = b2[j] + ((a0 + a1) + (a2 + a3));
        logit = fmaf(fmaxf(acc, 0.f), W3[j], logit);
    }
    tbl[i] = 1.f / (1.f + expf(-logit));
}

// Kernel 1b: pack scalar table into (g[i], g[i+1]) pairs -> one 8B load per step.
__global__ void pack_table_kernel(const float* __restrict__ g, float2* __restrict__ tbl2, int n)
{
    int i = blockIdx.x * blockDim.x + threadIdx.x;
    if (i > n) return;
    tbl2[i] = make_float2(g[i], g[i + 1]);
}

// Kernel 2: coalesced LDS-staged row update, 4 independent chains per thread.
#define ROWS_PER_BLOCK 1024
#define BLOCK 256
#define RPT 4   // rows per thread

__global__ __launch_bounds__(BLOCK)
void rows_kernel(const float* __restrict__ x, const float2* __restrict__ tbl2,
                 float* __restrict__ out, int B, int n, float lo, float inv_h)
{
    __shared__ float lds[ROWS_PER_BLOCK * 7];   // 28 KiB -> 5 blocks/CU
    const int tid = threadIdx.x;
    const long long rowBase = (long long)blockIdx.x * ROWS_PER_BLOCK;
    const int rows = min(ROWS_PER_BLOCK, (int)(B - rowBase));
    const int nfl  = rows * 7;
    const int nf4  = nfl >> 2;
    const size_t fBase = (size_t)rowBase * 7;   // multiple of 7168 -> 16B aligned

    // Coalesced float4 global -> LDS
    const float4* __restrict__ in4 = (const float4*)(x + fBase);
    float4* lds4 = (float4*)lds;
    for (int i = tid; i < nf4; i += BLOCK) lds4[i] = in4[i];
    for (int i = (nf4 << 2) + tid; i < nfl; i += BLOCK) lds[i] = x[fBase + i];
    __syncthreads();

    if (rows == ROWS_PER_BLOCK) {
        // Full block: RPT independent recurrence chains per thread, interleaved
        // so RPT table loads are in flight at once (latency / RPT).
        float x2v[RPT], fv[RPT], x3v[RPT], x4v[RPT], x5v[RPT];
#pragma unroll
        for (int k = 0; k < RPT; ++k) {
            const float* row = lds + (tid + k * BLOCK) * 7;
            x2v[k] = row[2];
            float x6 = row[6];
            fv[k] = (x6 <= 0.f) ? (x6 + 1.f) : (1.f - x6);
        }
#pragma unroll
        for (int s = 0; s < 10; ++s) {
#pragma unroll
            for (int k = 0; k < RPT; ++k) {
                float t = x2v[k] * fv[k];
                x4v[k] = t + LAT_CONST;
                x5v[k] = t * SEND_CONST;
                x3v[k] = x4v[k] * GRAD_CONST;
                float p = (t - lo) * inv_h;
                p = fminf(fmaxf(p, 0.f), (float)n);
                int   idx = (int)p;
                float fr  = p - (float)idx;
                float2 e  = tbl2[idx];
                x2v[k] = fmaf(e.y - e.x, fr, e.x);   // lerp = sigmoid(MLP(feat))
            }
        }
#pragma unroll
        for (int k = 0; k < RPT; ++k) {
            float* row = lds + (tid + k * BLOCK) * 7;
            row[0] += 10.f;
            row[2] = x2v[k];
            row[3] = x3v[k];
            row[4] = x4v[k];
            row[5] = x5v[k];
        }
    } else {
        // Tail block (one per grid): simple per-row path.
        for (int r = tid; r < rows; r += BLOCK) {
            float* row = lds + r * 7;
            float x2 = row[2];
            float x6 = row[6];
            float f = (x6 <= 0.f) ? (x6 + 1.f) : (1.f - x6);
            float x3 = 0.f, x4 = 0.f, x5 = 0.f;
#pragma unroll
            for (int s = 0; s < 10; ++s) {
                float t = x2 * f;
                x4 = t + LAT_CONST;
                x5 = t * SEND_CONST;
                x3 = x4 * GRAD_CONST;
                float p = (t - lo) * inv_h;
                p = fminf(fmaxf(p, 0.f), (float)n);
                int   idx = (int)p;
                float fr  = p - (float)idx;
                float2 e  = tbl2[idx];
                x2 = fmaf(e.y - e.x, fr, e.x);
            }
            row[0] += 10.f;
            row[2] = x2; row[3] = x3; row[4] = x4; row[5] = x5;
        }
    }
    __syncthreads();

    // Coalesced float4 LDS -> global
    float4* __restrict__ out4 = (float4*)(out + fBase);
    for (int i = tid; i < nf4; i += BLOCK) out4[i] = lds4[i];
    for (int i = (nf4 << 2) + tid; i < nfl; i += BLOCK) out[fBase + i] = lds[i];
}

extern "C" void kernel_launch(void* const* d_in, const int* in_sizes, int n_in,
                              void* d_out, int out_size, void* d_ws, size_t ws_size,
                              hipStream_t stream)
{
    const float* x  = (const float*)d_in[0];
    const float* W1 = (const float*)d_in[1];
    const float* b1 = (const float*)d_in[2];
    const float* W2 = (const float*)d_in[3];
    const float* b2 = (const float*)d_in[4];
    const float* W3 = (const float*)d_in[5];
    const float* b3 = (const float*)d_in[6];
    float* out = (float*)d_out;

    int B = in_sizes[0] / 7;

    // Table: 64K entries. ws layout: [float2 tbl2 (n+1)] [float g (n+2)].
    int n = 1 << 16;
    while ((size_t)(n + 1) * sizeof(float2) + (size_t)(n + 2) * sizeof(float) > ws_size
           && n > 1024) n >>= 1;

    float2* tbl2 = (float2*)d_ws;
    float*  g    = (float*)((char*)d_ws + (size_t)(n + 1) * sizeof(float2));
    const float lo = -24.f, hi = 24.f;
    float h     = (hi - lo) / (float)n;
    float inv_h = (float)n / (hi - lo);

    hipLaunchKernelGGL(build_table_kernel, dim3((n + 2 + 255) / 256), dim3(256), 0, stream,
                       W1, b1, W2, b2, W3, b3, g, n, lo, h);
    hipLaunchKernelGGL(pack_table_kernel, dim3((n + 1 + 255) / 256), dim3(256), 0, stream,
                       g, tbl2, n);
    hipLaunchKernelGGL(rows_kernel, dim3((B + ROWS_PER_BLOCK - 1) / ROWS_PER_BLOCK), dim3(BLOCK),
                       0, stream, x, tbl2, out, B, n, lo, inv_h);
}

// Round 5
// 67.135 us; speedup vs baseline: 1.0325x; 1.0122x over previous
//
#include <hip/hip_runtime.h>
#include <math.h>

#define LAT_CONST  ((float)(5.0 * 0.03 / 200.0 + 0.06))   // 0.06075
#define GRAD_CONST ((float)(1.0 / 0.06))                  // 16.666666...
#define SEND_CONST ((float)(2.0 / 3.0))                   // 0.666666...

// Wide table (step 1): covers t = x2_init * f, |t| < ~23.
#define LO1 (-24.f)
#define HI1 (24.f)
// Narrow table (steps 2..10): x2 in (0,1), f in (-6.5, 1] => t in (-6.5, 1.5).
#define N2  6144
#define LO2 (-6.5f)
#define HI2 (1.5f)
#define H2  ((HI2 - LO2) / (float)N2)      // 1.302e-3
#define IH2 ((float)N2 / (HI2 - LO2))      // 768
#define C2  (-LO2 * IH2)                   // 4992

// Kernel 1: tabulate g(t) = sigmoid(MLP([x3,x4,x5](t))) for BOTH tables in one
// launch (wide: n1+2 entries, narrow: N2+2 entries). 8 partial accumulators
// keep 8 FMA chains in flight (this launch runs at ~1 wave/SIMD -> dep-latency
// bound, not throughput bound).
__global__ void build_table_kernel(const float* __restrict__ W1, const float* __restrict__ b1,
                                   const float* __restrict__ W2, const float* __restrict__ b2,
                                   const float* __restrict__ W3, const float* __restrict__ b3,
                                   float* __restrict__ g1, float* __restrict__ g2,
                                   int n1, float h1)
{
    int i = blockIdx.x * blockDim.x + threadIdx.x;
    int n1e = n1 + 2;
    if (i >= n1e + N2 + 2) return;

    float t;
    float* dst;
    if (i < n1e) { t = LO1 + (float)i * h1;         dst = g1 + i; }
    else         { int j = i - n1e;
                   t = LO2 + (float)j * H2;          dst = g2 + j; }

    float x4 = t + LAT_CONST;
    float x5 = t * SEND_CONST;
    float x3 = x4 * GRAD_CONST;

    float h1v[64];
#pragma unroll
    for (int j = 0; j < 64; ++j) {
        float acc = b1[j];
        acc = fmaf(x3, W1[j],       acc);
        acc = fmaf(x4, W1[64 + j],  acc);
        acc = fmaf(x5, W1[128 + j], acc);
        h1v[j] = fmaxf(acc, 0.f);
    }

    float logit = b3[0];
    for (int j = 0; j < 64; ++j) {
        float a0 = 0.f, a1 = 0.f, a2 = 0.f, a3 = 0.f;
        float a4 = 0.f, a5 = 0.f, a6 = 0.f, a7 = 0.f;
#pragma unroll
        for (int k = 0; k < 64; k += 8) {
            a0 = fmaf(h1v[k + 0], W2[(k + 0) * 64 + j], a0);
            a1 = fmaf(h1v[k + 1], W2[(k + 1) * 64 + j], a1);
            a2 = fmaf(h1v[k + 2], W2[(k + 2) * 64 + j], a2);
            a3 = fmaf(h1v[k + 3], W2[(k + 3) * 64 + j], a3);
            a4 = fmaf(h1v[k + 4], W2[(k + 4) * 64 + j], a4);
            a5 = fmaf(h1v[k + 5], W2[(k + 5) * 64 + j], a5);
            a6 = fmaf(h1v[k + 6], W2[(k + 6) * 64 + j], a6);
            a7 = fmaf(h1v[k + 7], W2[(k + 7) * 64 + j], a7);
        }
        float acc = b2[j] + (((a0 + a1) + (a2 + a3)) + ((a4 + a5) + (a6 + a7)));
        logit = fmaf(fmaxf(acc, 0.f), W3[j], logit);
    }
    *dst = 1.f / (1.f + expf(-logit));
}

// Kernel 1b: pack both scalar tables into (g[i], g[i+1]) float2 pairs.
__global__ void pack_table_kernel(const float* __restrict__ g1, float2* __restrict__ t2w,
                                  const float* __restrict__ g2, float2* __restrict__ t2n,
                                  int n1)
{
    int i = blockIdx.x * blockDim.x + threadIdx.x;
    if (i <= n1) { t2w[i] = make_float2(g1[i], g1[i + 1]); return; }
    int j = i - (n1 + 1);
    if (j <= N2) t2n[j] = make_float2(g2[j], g2[j + 1]);
}

// Kernel 2: coalesced LDS-staged row update. Step 1 gathers from the wide L2
// table; steps 2..10 gather from the narrow LDS-resident table (removes ~90%
// of the random 64B-line L2 gather traffic that bounded R3 at ~30 TB/s L2).
#define ROWS_PER_BLOCK 1024
#define BLOCK 256
#define RPT 4   // rows per thread

__global__ __launch_bounds__(BLOCK)
void rows_kernel(const float* __restrict__ x, const float2* __restrict__ t2w,
                 const float2* __restrict__ t2n, float* __restrict__ out,
                 int B, int n1, float inv_h1, float c1)
{
    __shared__ float lds[ROWS_PER_BLOCK * 7];            // 28 KiB
    __shared__ __align__(16) float2 tn[N2 + 1];          // 48 KiB -> total 76KiB, 2 blocks/CU

    const int tid = threadIdx.x;

    // Narrow table global -> LDS (broadcast copy, L2/L3-hot, float4 coalesced).
    {
        const float4* s4 = (const float4*)t2n;           // (N2+1)*2 = 12290 floats
        float4* d4 = (float4*)tn;
        for (int i = tid; i < (N2 * 2) / 4; i += BLOCK) d4[i] = s4[i];  // 3072 float4
        if (tid == 0) tn[N2] = t2n[N2];                  // trailing entry
    }

    const long long rowBase = (long long)blockIdx.x * ROWS_PER_BLOCK;
    const int rows = min(ROWS_PER_BLOCK, (int)(B - rowBase));
    const int nfl  = rows * 7;
    const int nf4  = nfl >> 2;
    const size_t fBase = (size_t)rowBase * 7;            // multiple of 7168 -> 16B aligned

    // Coalesced float4 global -> LDS
    const float4* __restrict__ in4 = (const float4*)(x + fBase);
    float4* lds4 = (float4*)lds;
    for (int i = tid; i < nf4; i += BLOCK) lds4[i] = in4[i];
    for (int i = (nf4 << 2) + tid; i < nfl; i += BLOCK) lds[i] = x[fBase + i];
    __syncthreads();

    if (rows == ROWS_PER_BLOCK) {
        float x2v[RPT], fv[RPT], tv[RPT];
#pragma unroll
        for (int k = 0; k < RPT; ++k) {
            const float* row = lds + (tid + k * BLOCK) * 7;
            x2v[k] = row[2];
            float x6 = row[6];
            fv[k] = (x6 <= 0.f) ? (x6 + 1.f) : (1.f - x6);   // loop constant
        }
        // Step 1: wide-range gather from global (L2).
#pragma unroll
        for (int k = 0; k < RPT; ++k) {
            float t = x2v[k] * fv[k];
            tv[k] = t;
            float p = fmaf(t, inv_h1, c1);
            p = fminf(fmaxf(p, 0.f), (float)n1);
            int   idx = (int)p;
            float fr  = p - (float)idx;
            float2 e  = t2w[idx];
            x2v[k] = fmaf(e.y - e.x, fr, e.x);
        }
        // Steps 2..10: narrow-range gather from LDS.
#pragma unroll
        for (int s = 1; s < 10; ++s) {
#pragma unroll
            for (int k = 0; k < RPT; ++k) {
                float t = x2v[k] * fv[k];
                tv[k] = t;
                float p = fmaf(t, IH2, C2);
                p = fminf(fmaxf(p, 0.f), (float)N2);
                int   idx = (int)p;
                float fr  = p - (float)idx;
                float2 e  = tn[idx];
                x2v[k] = fmaf(e.y - e.x, fr, e.x);
            }
        }
        // x3/x4/x5 only survive from the LAST step -> computed once here.
#pragma unroll
        for (int k = 0; k < RPT; ++k) {
            float* row = lds + (tid + k * BLOCK) * 7;
            float x4 = tv[k] + LAT_CONST;
            row[0] += 10.f;                 // 10 steps of +1
            row[2] = x2v[k];
            row[3] = x4 * GRAD_CONST;
            row[4] = x4;
            row[5] = tv[k] * SEND_CONST;
        }
    } else {
        // Tail block (at most one per grid).
        for (int r = tid; r < rows; r += BLOCK) {
            float* row = lds + r * 7;
            float x2 = row[2];
            float x6 = row[6];
            float f = (x6 <= 0.f) ? (x6 + 1.f) : (1.f - x6);
            float tl = 0.f;
#pragma unroll
            for (int s = 0; s < 10; ++s) {
                float t = x2 * f;
                tl = t;
                float p, fr; int idx; float2 e;
                if (s == 0) {
                    p = fmaf(t, inv_h1, c1);
                    p = fminf(fmaxf(p, 0.f), (float)n1);
                    idx = (int)p; fr = p - (float)idx;
                    e = t2w[idx];
                } else {
                    p = fmaf(t, IH2, C2);
                    p = fminf(fmaxf(p, 0.f), (float)N2);
                    idx = (int)p; fr = p - (float)idx;
                    e = tn[idx];
                }
                x2 = fmaf(e.y - e.x, fr, e.x);
            }
            float x4 = tl + LAT_CONST;
            row[0] += 10.f;
            row[2] = x2;
            row[3] = x4 * GRAD_CONST;
            row[4] = x4;
            row[5] = tl * SEND_CONST;
        }
    }
    __syncthreads();

    // Coalesced float4 LDS -> global
    float4* __restrict__ out4 = (float4*)(out + fBase);
    for (int i = tid; i < nf4; i += BLOCK) out4[i] = lds4[i];
    for (int i = (nf4 << 2) + tid; i < nfl; i += BLOCK) out[fBase + i] = lds[i];
}

static inline size_t align16(size_t v) { return (v + 15) & ~(size_t)15; }

extern "C" void kernel_launch(void* const* d_in, const int* in_sizes, int n_in,
                              void* d_out, int out_size, void* d_ws, size_t ws_size,
                              hipStream_t stream)
{
    const float* x  = (const float*)d_in[0];
    const float* W1 = (const float*)d_in[1];
    const float* b1 = (const float*)d_in[2];
    const float* W2 = (const float*)d_in[3];
    const float* b2 = (const float*)d_in[4];
    const float* W3 = (const float*)d_in[5];
    const float* b3 = (const float*)d_in[6];
    float* out = (float*)d_out;

    int B = in_sizes[0] / 7;

    // ws layout: [t2w (n1+1) f2][t2n (N2+1) f2][g1 (n1+2) f][g2 (N2+2) f]
    int n1 = 1 << 16;
    while (align16((size_t)(n1 + 1) * 8) + align16((size_t)(N2 + 1) * 8) +
           align16((size_t)(n1 + 2) * 4) + (size_t)(N2 + 2) * 4 > ws_size && n1 > 1024)
        n1 >>= 1;

    char* ws = (char*)d_ws;
    size_t off = 0;
    float2* t2w = (float2*)(ws + off); off += align16((size_t)(n1 + 1) * 8);
    float2* t2n = (float2*)(ws + off); off += align16((size_t)(N2 + 1) * 8);
    float*  g1  = (float*)(ws + off);  off += align16((size_t)(n1 + 2) * 4);
    float*  g2  = (float*)(ws + off);

    float h1     = (HI1 - LO1) / (float)n1;
    float inv_h1 = (float)n1 / (HI1 - LO1);
    float c1     = -LO1 * inv_h1;

    int nbuild = n1 + 2 + N2 + 2;
    hipLaunchKernelGGL(build_table_kernel, dim3((nbuild + 255) / 256), dim3(256), 0, stream,
                       W1, b1, W2, b2, W3, b3, g1, g2, n1, h1);
    int npack = n1 + 1 + N2 + 1;
    hipLaunchKernelGGL(pack_table_kernel, dim3((npack + 255) / 256), dim3(256), 0, stream,
                       g1, t2w, g2, t2n, n1);
    hipLaunchKernelGGL(rows_kernel, dim3((B + ROWS_PER_BLOCK - 1) / ROWS_PER_BLOCK), dim3(BLOCK),
                       0, stream, x, t2w, t2n, out, B, n1, inv_h1, c1);
}

// Round 6
// 54.413 us; speedup vs baseline: 1.2740x; 1.2338x over previous
//
#include <hip/hip_runtime.h>
#include <math.h>

#define LAT_CONST  ((float)(5.0 * 0.03 / 200.0 + 0.06))   // 0.06075
#define GRAD_CONST ((float)(1.0 / 0.06))                  // 16.666666...
#define SEND_CONST ((float)(2.0 / 3.0))                   // 0.666666...

// Wide table (step 1 only, global/L2): covers t = x2_init * f.
#define LO1 (-24.f)
#define HI1 (24.f)
// Narrow table (steps 2..10, LDS-resident scalar): x2 in (0,1), f in (-5.8, 1].
#define N2  2048
#define LO2 (-6.25f)
#define HI2 (1.25f)
#define H2  ((HI2 - LO2) / (float)N2)          // 3.662e-3
#define IH2 ((float)N2 / (HI2 - LO2))          // 273.0667
#define C2  (-LO2 * IH2)                       // 1706.667

// Kernel 1: tabulate g(t) = sigmoid(MLP([x3,x4,x5](t))) for BOTH tables.
// 8 partial accumulators: this launch runs at ~1 wave/SIMD (latency-bound).
__global__ void build_table_kernel(const float* __restrict__ W1, const float* __restrict__ b1,
                                   const float* __restrict__ W2, const float* __restrict__ b2,
                                   const float* __restrict__ W3, const float* __restrict__ b3,
                                   float* __restrict__ g1, float* __restrict__ g2,
                                   int n1, float h1)
{
    int i = blockIdx.x * blockDim.x + threadIdx.x;
    int n1e = n1 + 2;
    if (i >= n1e + N2 + 2) return;

    float t;
    float* dst;
    if (i < n1e) { t = LO1 + (float)i * h1;  dst = g1 + i; }
    else         { int j = i - n1e;
                   t = LO2 + (float)j * H2;  dst = g2 + j; }

    float x4 = t + LAT_CONST;
    float x5 = t * SEND_CONST;
    float x3 = x4 * GRAD_CONST;

    float h1v[64];
#pragma unroll
    for (int j = 0; j < 64; ++j) {
        float acc = b1[j];
        acc = fmaf(x3, W1[j],       acc);
        acc = fmaf(x4, W1[64 + j],  acc);
        acc = fmaf(x5, W1[128 + j], acc);
        h1v[j] = fmaxf(acc, 0.f);
    }

    float logit = b3[0];
    for (int j = 0; j < 64; ++j) {
        float a0 = 0.f, a1 = 0.f, a2 = 0.f, a3 = 0.f;
        float a4 = 0.f, a5 = 0.f, a6 = 0.f, a7 = 0.f;
#pragma unroll
        for (int k = 0; k < 64; k += 8) {
            a0 = fmaf(h1v[k + 0], W2[(k + 0) * 64 + j], a0);
            a1 = fmaf(h1v[k + 1], W2[(k + 1) * 64 + j], a1);
            a2 = fmaf(h1v[k + 2], W2[(k + 2) * 64 + j], a2);
            a3 = fmaf(h1v[k + 3], W2[(k + 3) * 64 + j], a3);
            a4 = fmaf(h1v[k + 4], W2[(k + 4) * 64 + j], a4);
            a5 = fmaf(h1v[k + 5], W2[(k + 5) * 64 + j], a5);
            a6 = fmaf(h1v[k + 6], W2[(k + 6) * 64 + j], a6);
            a7 = fmaf(h1v[k + 7], W2[(k + 7) * 64 + j], a7);
        }
        float acc = b2[j] + (((a0 + a1) + (a2 + a3)) + ((a4 + a5) + (a6 + a7)));
        logit = fmaf(fmaxf(acc, 0.f), W3[j], logit);
    }
    *dst = 1.f / (1.f + expf(-logit));
}

// Kernel 2: coalesced LDS-staged row update.
// Step 1 gathers from the wide global table (L2); steps 2..10 gather from an
// 8.2 KB scalar LDS table. Total LDS 36.9 KB -> 4 blocks/CU (50% occ cap).
#define ROWS_PER_BLOCK 1024
#define BLOCK 256
#define RPT 4

__global__ __launch_bounds__(BLOCK)
void rows_kernel(const float* __restrict__ x, const float* __restrict__ g1,
                 const float* __restrict__ g2, float* __restrict__ out,
                 int B, int n1, float inv_h1, float c1)
{
    __shared__ float lds[ROWS_PER_BLOCK * 7];        // 28 KiB
    __shared__ __align__(16) float tn[N2 + 2];       // 8.2 KiB scalar narrow table

    const int tid = threadIdx.x;

    // Narrow table global -> LDS (coalesced float4; 2050 floats).
    {
        const float4* s4 = (const float4*)g2;
        float4* d4 = (float4*)tn;
        for (int i = tid; i < N2 / 4; i += BLOCK) d4[i] = s4[i];   // 512 f4 = 2048 floats
        if (tid < 2) tn[N2 + tid] = g2[N2 + tid];
    }

    const long long rowBase = (long long)blockIdx.x * ROWS_PER_BLOCK;
    const int rows = min(ROWS_PER_BLOCK, (int)(B - rowBase));
    const int nfl  = rows * 7;
    const int nf4  = nfl >> 2;
    const size_t fBase = (size_t)rowBase * 7;        // multiple of 7168 -> 16B aligned

    // Coalesced float4 global -> LDS
    const float4* __restrict__ in4 = (const float4*)(x + fBase);
    float4* lds4 = (float4*)lds;
    for (int i = tid; i < nf4; i += BLOCK) lds4[i] = in4[i];
    for (int i = (nf4 << 2) + tid; i < nfl; i += BLOCK) lds[i] = x[fBase + i];
    __syncthreads();

    if (rows == ROWS_PER_BLOCK) {
        float x2v[RPT], fv[RPT], af2[RPT];
#pragma unroll
        for (int k = 0; k < RPT; ++k) {
            const float* row = lds + (tid + k * BLOCK) * 7;
            x2v[k] = row[2];
            float x6 = row[6];
            fv[k]  = (x6 <= 0.f) ? (x6 + 1.f) : (1.f - x6);   // loop constant
            af2[k] = fv[k] * IH2;                              // fold f into index scale
        }
        // Step 1: wide gather from global (L2). p = (x2*f - LO1)*inv_h1.
#pragma unroll
        for (int k = 0; k < RPT; ++k) {
            float p = fmaf(x2v[k], fv[k] * inv_h1, c1);
            p = fminf(fmaxf(p, 0.f), (float)n1);
            int   idx = (int)p;
            float fr  = p - (float)idx;
            float e0 = g1[idx], e1 = g1[idx + 1];
            x2v[k] = fmaf(e1 - e0, fr, e0);
        }
        // Steps 2..9: narrow gathers from LDS (8 steps).
#pragma unroll
        for (int s = 0; s < 8; ++s) {
#pragma unroll
            for (int k = 0; k < RPT; ++k) {
                float p = fmaf(x2v[k], af2[k], C2);
                p = fminf(fmaxf(p, 0.f), (float)N2);
                int   idx = (int)p;
                float fr  = p - (float)idx;
                float e0 = tn[idx], e1 = tn[idx + 1];   // ds_read2_b32
                x2v[k] = fmaf(e1 - e0, fr, e0);
            }
        }
        // Step 10: need t explicitly for the x3/x4/x5 outputs.
#pragma unroll
        for (int k = 0; k < RPT; ++k) {
            float t = x2v[k] * fv[k];
            float p = fmaf(t, IH2, C2);
            p = fminf(fmaxf(p, 0.f), (float)N2);
            int   idx = (int)p;
            float fr  = p - (float)idx;
            float e0 = tn[idx], e1 = tn[idx + 1];
            float x2f = fmaf(e1 - e0, fr, e0);

            float* row = lds + (tid + k * BLOCK) * 7;
            float x4 = t + LAT_CONST;
            row[0] += 10.f;                 // 10 steps of +1
            row[2] = x2f;
            row[3] = x4 * GRAD_CONST;
            row[4] = x4;
            row[5] = t * SEND_CONST;
        }
    } else {
        // Tail block (at most one per grid).
        for (int r = tid; r < rows; r += BLOCK) {
            float* row = lds + r * 7;
            float x2 = row[2];
            float x6 = row[6];
            float f = (x6 <= 0.f) ? (x6 + 1.f) : (1.f - x6);
            // step 1 (wide)
            {
                float p = fmaf(x2, f * inv_h1, c1);
                p = fminf(fmaxf(p, 0.f), (float)n1);
                int idx = (int)p; float fr = p - (float)idx;
                float e0 = g1[idx], e1 = g1[idx + 1];
                x2 = fmaf(e1 - e0, fr, e0);
            }
            // steps 2..9
            for (int s = 0; s < 8; ++s) {
                float p = fmaf(x2, f * IH2, C2);
                p = fminf(fmaxf(p, 0.f), (float)N2);
                int idx = (int)p; float fr = p - (float)idx;
                float e0 = tn[idx], e1 = tn[idx + 1];
                x2 = fmaf(e1 - e0, fr, e0);
            }
            // step 10
            float t = x2 * f;
            float p = fmaf(t, IH2, C2);
            p = fminf(fmaxf(p, 0.f), (float)N2);
            int idx = (int)p; float fr = p - (float)idx;
            float e0 = tn[idx], e1 = tn[idx + 1];
            float x2f = fmaf(e1 - e0, fr, e0);
            float x4 = t + LAT_CONST;
            row[0] += 10.f;
            row[2] = x2f;
            row[3] = x4 * GRAD_CONST;
            row[4] = x4;
            row[5] = t * SEND_CONST;
        }
    }
    __syncthreads();

    // Coalesced float4 LDS -> global
    float4* __restrict__ out4 = (float4*)(out + fBase);
    for (int i = tid; i < nf4; i += BLOCK) out4[i] = lds4[i];
    for (int i = (nf4 << 2) + tid; i < nfl; i += BLOCK) out[fBase + i] = lds[i];
}

static inline size_t align16(size_t v) { return (v + 15) & ~(size_t)15; }

extern "C" void kernel_launch(void* const* d_in, const int* in_sizes, int n_in,
                              void* d_out, int out_size, void* d_ws, size_t ws_size,
                              hipStream_t stream)
{
    const float* x  = (const float*)d_in[0];
    const float* W1 = (const float*)d_in[1];
    const float* b1 = (const float*)d_in[2];
    const float* W2 = (const float*)d_in[3];
    const float* b2 = (const float*)d_in[4];
    const float* W3 = (const float*)d_in[5];
    const float* b3 = (const float*)d_in[6];
    float* out = (float*)d_out;

    int B = in_sizes[0] / 7;

    // ws layout: [g1 (n1+2) floats][g2 (N2+2) floats]
    int n1 = 1 << 16;
    while (align16((size_t)(n1 + 2) * 4) + (size_t)(N2 + 2) * 4 > ws_size && n1 > 1024)
        n1 >>= 1;

    char* ws = (char*)d_ws;
    float* g1 = (float*)ws;
    float* g2 = (float*)(ws + align16((size_t)(n1 + 2) * 4));

    float h1     = (HI1 - LO1) / (float)n1;
    float inv_h1 = (float)n1 / (HI1 - LO1);
    float c1     = -LO1 * inv_h1;

    int nbuild = n1 + 2 + N2 + 2;
    hipLaunchKernelGGL(build_table_kernel, dim3((nbuild + 255) / 256), dim3(256), 0, stream,
                       W1, b1, W2, b2, W3, b3, g1, g2, n1, h1);
    hipLaunchKernelGGL(rows_kernel, dim3((B + ROWS_PER_BLOCK - 1) / ROWS_PER_BLOCK), dim3(BLOCK),
                       0, stream, x, g1, g2, out, B, n1, inv_h1, c1);
}